// Round 16
// baseline (361.592 us; speedup 1.0000x reference)
//
#include <hip/hip_runtime.h>
#include <hip/hip_bf16.h>
#include <cstddef>

// ---------------- problem constants ----------------
constexpr int Ll   = 13294;
constexpr int NROW = 4 * Ll;     // 53176
constexpr int MP   = 53248;      // rows padded to multiple of 128

typedef __bf16       bf8v __attribute__((ext_vector_type(8)));
typedef __bf16       bf2v __attribute__((ext_vector_type(2)));
typedef float        f4v  __attribute__((ext_vector_type(4)));
typedef unsigned int u4v  __attribute__((ext_vector_type(4)));

#if defined(__has_builtin)
#  if __has_builtin(__builtin_amdgcn_fdot2_f32_bf16)
#    define HAVE_DOT2_BF16 1
#  endif
#endif
#ifndef HAVE_DOT2_BF16
#  define HAVE_DOT2_BF16 0
#endif

// drain own loads (vm + lds) then raw barrier  [T3/T4 minimum-2-phase recipe]
#define WAIT_BARRIER() do { \
    asm volatile("s_waitcnt vmcnt(0) lgkmcnt(0)" ::: "memory"); \
    __builtin_amdgcn_s_barrier(); } while (0)

// XCD-aware chunked remap (requires nwg % 8 == 0)  [T1, m157/m192]
__device__ __forceinline__ void xcd_remap(int& m0, int& n0)
{
    const int nwg  = gridDim.x * gridDim.y;
    const int flat = blockIdx.y * gridDim.x + blockIdx.x;
    const int w    = (flat & 7) * (nwg >> 3) + (flat >> 3);
    n0 = (w % gridDim.x) * 128;
    m0 = (w / gridDim.x) * 128;
}

__device__ __forceinline__ void gload16(const __hip_bfloat16* src, __hip_bfloat16* dst)
{
    __builtin_amdgcn_global_load_lds(
        (const __attribute__((address_space(1))) void*)src,
        (__attribute__((address_space(3))) void*)dst, 16, 0, 0);
}

// =====================================================================
// shared GEMM body: 128x128 tile, BK=32 double-buffered, prefetch-before-
// compute, 4 waves 2x2, global_load_lds 16B. Swapped-operand MFMA:
// row = m0+wm*64+mr*16+fr, col = n0+wn*64+nr*16+fq*4+j.
// A: [M][K] bf16 row-major. Bt: [N][K] bf16 (W^T). bias2: cols >= 256.
// =====================================================================
template<bool RELU, bool OUTF, bool OUTB>
__device__ __forceinline__
void gemm_body(const __hip_bfloat16* __restrict__ A, const __hip_bfloat16* __restrict__ Bt,
               const float* __restrict__ bias, const float* __restrict__ bias2,
               float* __restrict__ Cf, __hip_bfloat16* __restrict__ Cb,
               int N, int K, int m0, int n0,
               __hip_bfloat16 (*As)[128 * 32], __hip_bfloat16 (*Bs)[128 * 32])
{
    const int tid  = threadIdx.x;
    const int wid  = tid >> 6;
    const int lane = tid & 63;
    const int wm = wid >> 1, wn = wid & 1;
    const int fr = lane & 15, fq = lane >> 4;
    const int sr = lane >> 2;
    const int sc = (lane & 3) * 8;

    f4v acc[4][4] = {};   // [nr][mr]

    auto stage = [&](int buf, int kk) {
        #pragma unroll
        for (int i = 0; i < 2; ++i) {
            const int s = wid * 2 + i;
            gload16(A  + (size_t)(m0 + s * 16 + sr) * K + kk + sc, &As[buf][s * 512]);
            gload16(Bt + (size_t)(n0 + s * 16 + sr) * K + kk + sc, &Bs[buf][s * 512]);
        }
    };
    auto compute = [&](int buf) {
        bf8v a[4], b[4];
        #pragma unroll
        for (int r = 0; r < 4; ++r) {
            a[r] = __builtin_bit_cast(bf8v, *(const u4v*)&As[buf][(wm * 64 + r * 16 + fr) * 32 + fq * 8]);
            b[r] = __builtin_bit_cast(bf8v, *(const u4v*)&Bs[buf][(wn * 64 + r * 16 + fr) * 32 + fq * 8]);
        }
        __builtin_amdgcn_s_setprio(1);
        #pragma unroll
        for (int nr = 0; nr < 4; ++nr)
            #pragma unroll
            for (int mr = 0; mr < 4; ++mr)
                acc[nr][mr] = __builtin_amdgcn_mfma_f32_16x16x32_bf16(b[nr], a[mr], acc[nr][mr], 0, 0, 0);
        __builtin_amdgcn_s_setprio(0);
    };

    stage(0, 0);
    WAIT_BARRIER();
    for (int k0 = 0; k0 < K; k0 += 64) {
        stage(1, k0 + 32);
        compute(0);
        WAIT_BARRIER();
        if (k0 + 64 < K) stage(0, k0 + 64);
        compute(1);
        WAIT_BARRIER();
    }

    #pragma unroll
    for (int nr = 0; nr < 4; ++nr) {
        const int colbase = n0 + wn * 64 + nr * 16 + fq * 4;
        const float* bp = (bias2 != nullptr && colbase >= 256) ? (bias2 - 256) : bias;
        const float4 b4 = *(const float4*)&bp[colbase];
        #pragma unroll
        for (int mr = 0; mr < 4; ++mr) {
            const int row = m0 + wm * 64 + mr * 16 + fr;
            f4v v = acc[nr][mr];
            v[0] += b4.x; v[1] += b4.y; v[2] += b4.z; v[3] += b4.w;
            if (RELU) {
                v[0] = fmaxf(v[0], 0.f); v[1] = fmaxf(v[1], 0.f);
                v[2] = fmaxf(v[2], 0.f); v[3] = fmaxf(v[3], 0.f);
            }
            if (OUTF)
                *(float4*)&Cf[(size_t)row * N + colbase] = make_float4(v[0], v[1], v[2], v[3]);
            if (OUTB) {
                union { ushort4 u; __hip_bfloat16 h[4]; } pk;
                pk.h[0] = __float2bfloat16(v[0]); pk.h[1] = __float2bfloat16(v[1]);
                pk.h[2] = __float2bfloat16(v[2]); pk.h[3] = __float2bfloat16(v[3]);
                *(ushort4*)&Cb[(size_t)row * N + colbase] = pk.u;
            }
        }
    }
}

// ---- fused v-gemm + cat-gemm: one dispatch, 2080 blocks ----
__global__ __launch_bounds__(256)
void gemm_proj_pair(const __hip_bfloat16* __restrict__ qb, const __hip_bfloat16* __restrict__ qpb,
                    const __hip_bfloat16* __restrict__ vWt, const __hip_bfloat16* __restrict__ catWt,
                    const float* __restrict__ v_b, const float* __restrict__ off_b,
                    const float* __restrict__ aw_b,
                    __hip_bfloat16* __restrict__ vbuf, __hip_bfloat16* __restrict__ catb)
{
    __shared__ __hip_bfloat16 As[2][128 * 32];
    __shared__ __hip_bfloat16 Bs[2][128 * 32];
    const int nwg  = 2080;                         // 5 * 416, %8 == 0
    const int flat = blockIdx.x;
    const int w    = (flat & 7) * (nwg >> 3) + (flat >> 3);
    const int n    = w % 5, m = w / 5;
    if (n < 2)
        gemm_body<false, false, true>(qb, vWt, v_b, nullptr,
                                      nullptr, vbuf, 256, 256, m * 128, n * 128, As, Bs);
    else
        gemm_body<false, false, true>(qpb, catWt, off_b, aw_b,
                                      nullptr, catb, 384, 256, m * 128, (n - 2) * 128, As, Bs);
}

// =====================================================================
// ffn1 wide tile: 128x256, BK=32 double-buffered, 4 waves 2x2
// (wave = 64 rows x 128 cols, acc[8][4]). relu(x@w1+b1) -> bf16.
// =====================================================================
__global__ __launch_bounds__(256)
void gemm_wide(const __hip_bfloat16* __restrict__ A, const __hip_bfloat16* __restrict__ Bt,
               const float* __restrict__ bias, __hip_bfloat16* __restrict__ Cb)
{
    __shared__ __hip_bfloat16 As[2][128 * 32];
    __shared__ __hip_bfloat16 Bs[2][256 * 32];
    constexpr int N = 1024, K = 256;
    const int tid  = threadIdx.x;
    const int wid  = tid >> 6;
    const int lane = tid & 63;
    // XCD remap over 4 x 416 = 1664 blocks
    const int nwg  = gridDim.x * gridDim.y;
    const int flat = blockIdx.y * gridDim.x + blockIdx.x;
    const int w    = (flat & 7) * (nwg >> 3) + (flat >> 3);
    const int n0   = (w % gridDim.x) * 256;
    const int m0   = (w / gridDim.x) * 128;
    const int wm = wid >> 1, wn = wid & 1;     // wave: 64 rows x 128 cols
    const int fr = lane & 15, fq = lane >> 4;
    const int sr = lane >> 2;
    const int sc = (lane & 3) * 8;

    f4v acc[8][4] = {};   // [nr][mr]

    auto stage = [&](int buf, int kk) {
        #pragma unroll
        for (int i = 0; i < 2; ++i) {
            const int s = wid * 2 + i;
            gload16(A + (size_t)(m0 + s * 16 + sr) * K + kk + sc, &As[buf][s * 512]);
        }
        #pragma unroll
        for (int i = 0; i < 4; ++i) {
            const int s = wid * 4 + i;
            gload16(Bt + (size_t)(n0 + s * 16 + sr) * K + kk + sc, &Bs[buf][s * 512]);
        }
    };
    auto compute = [&](int buf) {
        bf8v a[4], b[8];
        #pragma unroll
        for (int r = 0; r < 4; ++r)
            a[r] = __builtin_bit_cast(bf8v, *(const u4v*)&As[buf][(wm * 64 + r * 16 + fr) * 32 + fq * 8]);
        #pragma unroll
        for (int r = 0; r < 8; ++r)
            b[r] = __builtin_bit_cast(bf8v, *(const u4v*)&Bs[buf][(wn * 128 + r * 16 + fr) * 32 + fq * 8]);
        __builtin_amdgcn_s_setprio(1);
        #pragma unroll
        for (int nr = 0; nr < 8; ++nr)
            #pragma unroll
            for (int mr = 0; mr < 4; ++mr)
                acc[nr][mr] = __builtin_amdgcn_mfma_f32_16x16x32_bf16(b[nr], a[mr], acc[nr][mr], 0, 0, 0);
        __builtin_amdgcn_s_setprio(0);
    };

    stage(0, 0);
    WAIT_BARRIER();
    for (int k0 = 0; k0 < K; k0 += 64) {
        stage(1, k0 + 32);
        compute(0);
        WAIT_BARRIER();
        if (k0 + 64 < K) stage(0, k0 + 64);
        compute(1);
        WAIT_BARRIER();
    }

    #pragma unroll
    for (int nr = 0; nr < 8; ++nr) {
        const int colbase = n0 + wn * 128 + nr * 16 + fq * 4;
        const float4 b4 = *(const float4*)&bias[colbase];
        #pragma unroll
        for (int mr = 0; mr < 4; ++mr) {
            const int row = m0 + wm * 64 + mr * 16 + fr;
            const f4v v = acc[nr][mr];
            union { ushort4 u; __hip_bfloat16 h[4]; } pk;
            pk.h[0] = __float2bfloat16(fmaxf(v[0] + b4.x, 0.f));
            pk.h[1] = __float2bfloat16(fmaxf(v[1] + b4.y, 0.f));
            pk.h[2] = __float2bfloat16(fmaxf(v[2] + b4.z, 0.f));
            pk.h[3] = __float2bfloat16(fmaxf(v[3] + b4.w, 0.f));
            *(ushort4*)&Cb[(size_t)row * N + colbase] = pk.u;
        }
    }
}

// =====================================================================
// bf16 MFMA GEMM (64x256 tile, N fixed 256, BK=32 double-buffered) +
// residual + LayerNorm epilogue. 4 waves 2x2, wave = 32 rows x 128 cols.
// =====================================================================
template<bool STOREB, bool RESB>
__global__ __launch_bounds__(256)
void gemm_ln(const __hip_bfloat16* __restrict__ A, const __hip_bfloat16* __restrict__ Bt,
             const float* __restrict__ bias,
             const float* __restrict__ resF, const __hip_bfloat16* __restrict__ resB,
             int Mres,
             const float* __restrict__ g, const float* __restrict__ be,
             float* __restrict__ outF, int MstoreF,
             __hip_bfloat16* __restrict__ outB,
             int K)
{
    __shared__ __hip_bfloat16 As[2][64 * 32];
    __shared__ __hip_bfloat16 Bs[2][256 * 32];
    __shared__ float red[2][64][2];
    const int tid  = threadIdx.x;
    const int wid  = tid >> 6;
    const int lane = tid & 63;
    const int m0 = blockIdx.x * 64;
    const int wm = wid >> 1, wn = wid & 1;     // wave: 32 rows x 128 cols
    const int fr = lane & 15, fq = lane >> 4;
    const int sr = lane >> 2;
    const int sc = (lane & 3) * 8;

    f4v acc[8][2] = {};   // [nr][mr]

    auto stage = [&](int buf, int kk) {
        gload16(A + (size_t)(m0 + wid * 16 + sr) * K + kk + sc, &As[buf][wid * 512]);
        #pragma unroll
        for (int i = 0; i < 4; ++i) {
            const int s = wid * 4 + i;
            gload16(Bt + (size_t)(s * 16 + sr) * K + kk + sc, &Bs[buf][s * 512]);
        }
    };
    auto compute = [&](int buf) {
        bf8v a[2], b[8];
        #pragma unroll
        for (int r = 0; r < 2; ++r)
            a[r] = __builtin_bit_cast(bf8v, *(const u4v*)&As[buf][(wm * 32 + r * 16 + fr) * 32 + fq * 8]);
        #pragma unroll
        for (int r = 0; r < 8; ++r)
            b[r] = __builtin_bit_cast(bf8v, *(const u4v*)&Bs[buf][(wn * 128 + r * 16 + fr) * 32 + fq * 8]);
        __builtin_amdgcn_s_setprio(1);
        #pragma unroll
        for (int nr = 0; nr < 8; ++nr)
            #pragma unroll
            for (int mr = 0; mr < 2; ++mr)
                acc[nr][mr] = __builtin_amdgcn_mfma_f32_16x16x32_bf16(b[nr], a[mr], acc[nr][mr], 0, 0, 0);
        __builtin_amdgcn_s_setprio(0);
    };

    stage(0, 0);
    WAIT_BARRIER();
    for (int k0 = 0; k0 < K; k0 += 64) {
        stage(1, k0 + 32);
        compute(0);
        WAIT_BARRIER();
        if (k0 + 64 < K) stage(0, k0 + 64);
        compute(1);
        WAIT_BARRIER();
    }

    float s2[2] = {}, q2[2] = {};
    #pragma unroll
    for (int nr = 0; nr < 8; ++nr) {
        const int colbase = wn * 128 + nr * 16 + fq * 4;
        const float4 b4 = *(const float4*)&bias[colbase];
        #pragma unroll
        for (int mr = 0; mr < 2; ++mr) {
            const int row = m0 + wm * 32 + mr * 16 + fr;
            f4v x = acc[nr][mr];
            x[0] += b4.x; x[1] += b4.y; x[2] += b4.z; x[3] += b4.w;
            if (RESB) {
                const ushort4 r4 = *(const ushort4*)&resB[(size_t)row * 256 + colbase];
                x[0] += __builtin_bit_cast(float, (unsigned)r4.x << 16);
                x[1] += __builtin_bit_cast(float, (unsigned)r4.y << 16);
                x[2] += __builtin_bit_cast(float, (unsigned)r4.z << 16);
                x[3] += __builtin_bit_cast(float, (unsigned)r4.w << 16);
            } else if (row < Mres) {
                const float4 r4 = *(const float4*)&resF[(size_t)row * 256 + colbase];
                x[0] += r4.x; x[1] += r4.y; x[2] += r4.z; x[3] += r4.w;
            }
            acc[nr][mr] = x;
            s2[mr] += x[0] + x[1] + x[2] + x[3];
            q2[mr] += x[0]*x[0] + x[1]*x[1] + x[2]*x[2] + x[3]*x[3];
        }
    }
    #pragma unroll
    for (int mr = 0; mr < 2; ++mr) {
        s2[mr] += __shfl_xor(s2[mr], 16, 64);
        q2[mr] += __shfl_xor(q2[mr], 16, 64);
        s2[mr] += __shfl_xor(s2[mr], 32, 64);
        q2[mr] += __shfl_xor(q2[mr], 32, 64);
    }
    if (fq == 0) {
        #pragma unroll
        for (int mr = 0; mr < 2; ++mr) {
            red[wn][wm * 32 + mr * 16 + fr][0] = s2[mr];
            red[wn][wm * 32 + mr * 16 + fr][1] = q2[mr];
        }
    }
    __syncthreads();
    float mean[2], rinv[2];
    #pragma unroll
    for (int mr = 0; mr < 2; ++mr) {
        const int r = wm * 32 + mr * 16 + fr;
        const float ss = red[0][r][0] + red[1][r][0];
        const float qq = red[0][r][1] + red[1][r][1];
        mean[mr] = ss * (1.f / 256.f);
        const float var = qq * (1.f / 256.f) - mean[mr] * mean[mr];
        rinv[mr] = rsqrtf(var + 1e-5f);
    }
    #pragma unroll
    for (int nr = 0; nr < 8; ++nr) {
        const int colbase = wn * 128 + nr * 16 + fq * 4;
        const float4 g4 = *(const float4*)&g[colbase];
        const float4 e4 = *(const float4*)&be[colbase];
        #pragma unroll
        for (int mr = 0; mr < 2; ++mr) {
            const int row = m0 + wm * 32 + mr * 16 + fr;
            const f4v x = acc[nr][mr];
            float y0 = (x[0] - mean[mr]) * rinv[mr] * g4.x + e4.x;
            float y1 = (x[1] - mean[mr]) * rinv[mr] * g4.y + e4.y;
            float y2 = (x[2] - mean[mr]) * rinv[mr] * g4.z + e4.z;
            float y3 = (x[3] - mean[mr]) * rinv[mr] * g4.w + e4.w;
            if (row < MstoreF)
                *(float4*)&outF[(size_t)row * 256 + colbase] = make_float4(y0, y1, y2, y3);
            if (STOREB) {
                union { ushort4 u; __hip_bfloat16 h[4]; } pk;
                pk.h[0] = __float2bfloat16(y0); pk.h[1] = __float2bfloat16(y1);
                pk.h[2] = __float2bfloat16(y2); pk.h[3] = __float2bfloat16(y3);
                *(ushort4*)&outB[(size_t)row * 256 + colbase] = pk.u;
            }
        }
    }
}

// =====================================================================
// prep_all: weight transpose+cvt (blocks 0..2943) and query/query+pos
// bf16 conversion (blocks 2944..9599) in ONE launch.
// =====================================================================
__global__ __launch_bounds__(256)
void prep_all(const float* __restrict__ vW, const float* __restrict__ offW,
              const float* __restrict__ awW, const float* __restrict__ outW,
              const float* __restrict__ w1, const float* __restrict__ w2,
              __hip_bfloat16* __restrict__ vWt, __hip_bfloat16* __restrict__ catWt,
              __hip_bfloat16* __restrict__ outWt, __hip_bfloat16* __restrict__ w1t,
              __hip_bfloat16* __restrict__ w2t,
              const float* __restrict__ q, const float* __restrict__ qp,
              __hip_bfloat16* __restrict__ qb, __hip_bfloat16* __restrict__ qpb)
{
    if (blockIdx.x < 2944) {
        int i = blockIdx.x * 256 + threadIdx.x;   // 753664 total
        if (i < 65536) { const int n = i >> 8, k = i & 255;
            vWt[i] = __float2bfloat16(vW[(size_t)k * 256 + n]); return; }
        i -= 65536;
        if (i < 98304) { const int n = i >> 8, k = i & 255;
            catWt[i] = __float2bfloat16(n < 256 ? offW[(size_t)k * 256 + n]
                                                : awW[(size_t)k * 128 + n - 256]); return; }
        i -= 98304;
        if (i < 65536) { const int n = i >> 8, k = i & 255;
            outWt[i] = __float2bfloat16(outW[(size_t)k * 256 + n]); return; }
        i -= 65536;
        if (i < 262144) { const int n = i >> 8, k = i & 255;
            w1t[i] = __float2bfloat16(w1[(size_t)k * 1024 + n]); return; }
        i -= 262144;
        { const int n = i >> 10, k = i & 1023;
            w2t[i] = __float2bfloat16(w2[(size_t)k * 256 + n]); }
        return;
    }
    const int i   = (blockIdx.x - 2944) * 256 + threadIdx.x;  // 8-elem chunk id
    const int row = i >> 5;
    union { u4v u; __hip_bfloat16 h[8]; } p1, p2;
    if (row >= NROW) {
        u4v z = {0u, 0u, 0u, 0u};
        p1.u = z; p2.u = z;
    } else {
        const size_t e = (size_t)i * 8;
        float4 x0 = *(const float4*)&q[e];
        float4 x1 = *(const float4*)&q[e + 4];
        float4 y0 = *(const float4*)&qp[e];
        float4 y1 = *(const float4*)&qp[e + 4];
        p1.h[0] = __float2bfloat16(x0.x); p1.h[1] = __float2bfloat16(x0.y);
        p1.h[2] = __float2bfloat16(x0.z); p1.h[3] = __float2bfloat16(x0.w);
        p1.h[4] = __float2bfloat16(x1.x); p1.h[5] = __float2bfloat16(x1.y);
        p1.h[6] = __float2bfloat16(x1.z); p1.h[7] = __float2bfloat16(x1.w);
        p2.h[0] = __float2bfloat16(x0.x + y0.x); p2.h[1] = __float2bfloat16(x0.y + y0.y);
        p2.h[2] = __float2bfloat16(x0.z + y0.z); p2.h[3] = __float2bfloat16(x0.w + y0.w);
        p2.h[4] = __float2bfloat16(x1.x + y1.x); p2.h[5] = __float2bfloat16(x1.y + y1.y);
        p2.h[6] = __float2bfloat16(x1.z + y1.z); p2.h[7] = __float2bfloat16(x1.w + y1.w);
    }
    *(u4v*)&qb[(size_t)i * 8]  = p1.u;
    *(u4v*)&qpb[(size_t)i * 8] = p2.u;
}

// =====================================================================
// MSDA sampling v5: bf16 cat input, packed weights, dot2 path,
// bijective XCD-chunked block remap. 40 VGPR / ~60% occupancy.
// At the L2-line-bandwidth roofline (~33 TB/s) — closed.
// =====================================================================
__device__ __forceinline__ float blo(unsigned u) { return __builtin_bit_cast(float, u << 16); }
__device__ __forceinline__ float bhi(unsigned u) { return __builtin_bit_cast(float, u & 0xffff0000u); }

__global__ __launch_bounds__(256)
void msda_sample5(const __hip_bfloat16* __restrict__ v, const __hip_bfloat16* __restrict__ cat,
                  const float* __restrict__ refp, __hip_bfloat16* __restrict__ accO)
{
    __shared__ int      sIdx[1024][4];
    __shared__ unsigned sWpk[1024][2];   // (w0,w1),(w2,w3) packed bf16
    // bijective XCD chunked remap (nwg = 6647 = 8*830+7 -> r=7, q=830) [m204]
    int blk;
    {
        const int nwg  = gridDim.x;
        const int q    = nwg >> 3;            // 830
        const int r    = nwg & 7;             // 7
        const int xcd  = blockIdx.x & 7;
        const int off  = blockIdx.x >> 3;
        blk = (xcd < r ? xcd * (q + 1) : r * (q + 1) + (xcd - r) * q) + off;
    }
    const int row0 = blk * 8;
    const int tid  = threadIdx.x;

    #pragma unroll
    for (int it = 0; it < 4; ++it) {
        const int item = it * 256 + tid;          // (r<<7)|(h<<4)|p
        const int p = item & 15, h = (item >> 4) & 7, r = item >> 7;
        const int row = row0 + r;
        const int lvl = p >> 2;
        const float logit = __bfloat162float(cat[(size_t)row * 384 + 256 + h * 16 + p]);
        float mx = logit;
        #pragma unroll
        for (int o = 1; o < 16; o <<= 1) mx = fmaxf(mx, __shfl_xor(mx, o, 64));
        const float e = __expf(logit - mx);
        float s = e;
        #pragma unroll
        for (int o = 1; o < 16; o <<= 1) s += __shfl_xor(s, o, 64);
        const float aw = e / s;

        const int Hs_[4] = {100, 50, 25, 13};
        const int Ss[4]  = {0, 10000, 12500, 13125};
        const int   Wl = Hs_[lvl];
        const float Wf = (float)Wl;
        const float ox = __bfloat162float(cat[(size_t)row * 384 + h * 32 + p * 2 + 0]);
        const float oy = __bfloat162float(cat[(size_t)row * 384 + h * 32 + p * 2 + 1]);
        const float rx = refp[(size_t)row * 8 + lvl * 2 + 0];
        const float ry = refp[(size_t)row * 8 + lvl * 2 + 1];
        const float x = (rx + ox / Wf) * Wf - 0.5f;
        const float y = (ry + oy / Wf) * Wf - 0.5f;
        const float x0f = floorf(x), y0f = floorf(y);
        const float lx = x - x0f, ly = y - y0f;
        const int x0 = (int)x0f, y0 = (int)y0f;
        const int b = row / Ll;
        const int vbase = b * Ll + Ss[lvl];
        int ixr[4]; unsigned short wb[4];
        #pragma unroll
        for (int c = 0; c < 4; ++c) {
            const int cy = c >> 1, cx = c & 1;
            const int yi = y0 + cy, xi = x0 + cx;
            const bool ok = (yi >= 0) & (yi < Wl) & (xi >= 0) & (xi < Wl);
            const int yc = min(max(yi, 0), Wl - 1);
            const int xc = min(max(xi, 0), Wl - 1);
            const float wt = (cy ? ly : 1.f - ly) * (cx ? lx : 1.f - lx);
            ixr[c] = (vbase + yc * Wl + xc) * 512;
            const __hip_bfloat16 hw = __float2bfloat16(ok ? aw * wt : 0.f);
            wb[c] = __builtin_bit_cast(unsigned short, hw);
        }
        const int item2 = (item & ~15) | ((item & 15) ^ h);  // bank swizzle
        *(int4*)&sIdx[item2][0] = make_int4(ixr[0], ixr[1], ixr[2], ixr[3]);
        sWpk[item2][0] = (unsigned)wb[0] | ((unsigned)wb[1] << 16);
        sWpk[item2][1] = (unsigned)wb[2] | ((unsigned)wb[3] << 16);
    }
    __syncthreads();

    const int r   = tid >> 5;
    const int h   = (tid >> 2) & 7;
    const int oct = tid & 3;
    const int row = row0 + r;
    const char* vB = (const char*)v + (h * 32 + oct * 8) * 2;
    const int ibase = r * 128 + h * 16;
    float acc[8] = {};
    #pragma unroll
    for (int i = 0; i < 16; ++i) {
        const int idx = ibase + (i ^ h);
        const int4  ix = *(const int4*)&sIdx[idx][0];
        const uint2 wp = *(const uint2*)&sWpk[idx][0];
        u4v u0 = *(const u4v*)(vB + (unsigned)ix.x);
        u4v u1 = *(const u4v*)(vB + (unsigned)ix.y);
        u4v u2 = *(const u4v*)(vB + (unsigned)ix.z);
        u4v u3 = *(const u4v*)(vB + (unsigned)ix.w);
#if HAVE_DOT2_BF16
        const bf2v w01 = __builtin_bit_cast(bf2v, wp.x);
        const bf2v w23 = __builtin_bit_cast(bf2v, wp.y);
        #pragma unroll
        for (int q = 0; q < 4; ++q) {
            const unsigned lo01 = __builtin_amdgcn_perm(u1[q], u0[q], 0x05040100u);
            const unsigned hi01 = __builtin_amdgcn_perm(u1[q], u0[q], 0x07060302u);
            const unsigned lo23 = __builtin_amdgcn_perm(u3[q], u2[q], 0x05040100u);
            const unsigned hi23 = __builtin_amdgcn_perm(u3[q], u2[q], 0x07060302u);
            acc[2*q]   = __builtin_amdgcn_fdot2_f32_bf16(__builtin_bit_cast(bf2v, lo01), w01, acc[2*q],   false);
            acc[2*q]   = __builtin_amdgcn_fdot2_f32_bf16(__builtin_bit_cast(bf2v, lo23), w23, acc[2*q],   false);
            acc[2*q+1] = __builtin_amdgcn_fdot2_f32_bf16(__builtin_bit_cast(bf2v, hi01), w01, acc[2*q+1], false);
            acc[2*q+1] = __builtin_amdgcn_fdot2_f32_bf16(__builtin_bit_cast(bf2v, hi23), w23, acc[2*q+1], false);
        }
#else
        const float w0 = blo(wp.x), w1 = bhi(wp.x);
        const float w2 = blo(wp.y), w3 = bhi(wp.y);
        #pragma unroll
        for (int q = 0; q < 4; ++q) {
            acc[2*q]   = fmaf(w0, blo(u0[q]), acc[2*q]);
            acc[2*q+1] = fmaf(w0, bhi(u0[q]), acc[2*q+1]);
            acc[2*q]   = fmaf(w1, blo(u1[q]), acc[2*q]);
            acc[2*q+1] = fmaf(w1, bhi(u1[q]), acc[2*q+1]);
            acc[2*q]   = fmaf(w2, blo(u2[q]), acc[2*q]);
            acc[2*q+1] = fmaf(w2, bhi(u2[q]), acc[2*q+1]);
            acc[2*q]   = fmaf(w3, blo(u3[q]), acc[2*q]);
            acc[2*q+1] = fmaf(w3, bhi(u3[q]), acc[2*q+1]);
        }
#endif
    }
    union { u4v u; __hip_bfloat16 hh[8]; } pk;
    #pragma unroll
    for (int q = 0; q < 8; ++q) pk.hh[q] = __float2bfloat16(acc[q]);
    *(u4v*)&accO[(size_t)row * 256 + h * 32 + oct * 8] = pk.u;
}

// =====================================================================
// launcher
// =====================================================================
extern "C" void kernel_launch(void* const* d_in, const int* in_sizes, int n_in,
                              void* d_out, int out_size, void* d_ws, size_t ws_size,
                              hipStream_t stream)
{
    (void)in_sizes; (void)n_in; (void)out_size; (void)ws_size;
    const float* query = (const float*)d_in[0];
    const float* qpos  = (const float*)d_in[1];
    const float* refp  = (const float*)d_in[2];
    const float* v_W   = (const float*)d_in[5];
    const float* v_b   = (const float*)d_in[6];
    const float* off_W = (const float*)d_in[7];
    const float* off_b = (const float*)d_in[8];
    const float* aw_W  = (const float*)d_in[9];
    const float* aw_b  = (const float*)d_in[10];
    const float* out_W = (const float*)d_in[11];
    const float* out_b = (const float*)d_in[12];
    const float* ln1g  = (const float*)d_in[13];
    const float* ln1b  = (const float*)d_in[14];
    const float* w1    = (const float*)d_in[15];
    const float* b1    = (const float*)d_in[16];
    const float* w2    = (const float*)d_in[17];
    const float* b2    = (const float*)d_in[18];
    const float* ln2g  = (const float*)d_in[19];
    const float* ln2b  = (const float*)d_in[20];
    float* out = (float*)d_out;

    char* ws = (char*)d_ws;
    // arena (peak ~137.9 MB) — live-range audited (round-11 layout):
    //   hbuf bf16 [MP][1024] : [0, 109.1M)            (written ffn1, read ffn2)
    //     inside hbuf's span, dead before ffn1:
    //     qb   bf16 [0, 27.3M)        (prep -> v-gemm A, LN1 residual; dead after LN1)
    //     qpb  bf16 [27.3M, 54.6M)    (prep -> cat-gemm A; reused as accb after)
    //     catb bf16 [54.6M, 95.5M)    (cat-gemm out -> msda; dead after msda)
    //   vbuf/xb bf16 [109.1M, 136.4M)  (v-gemm out -> msda; xb = LN1 out, live thru ffn2)
    //   weights [136.4M, 137.9M)
    constexpr size_t HALF_B = (size_t)MP * 256 * 2;     //  27,262,976
    constexpr size_t HBUF_B = (size_t)MP * 1024 * 2;    // 109,051,904
    __hip_bfloat16* hbuf = (__hip_bfloat16*)ws;
    __hip_bfloat16* qb   = (__hip_bfloat16*)ws;
    __hip_bfloat16* qpb  = (__hip_bfloat16*)(ws + HALF_B);
    __hip_bfloat16* catb = (__hip_bfloat16*)(ws + 2 * HALF_B);
    __hip_bfloat16* vbuf = (__hip_bfloat16*)(ws + HBUF_B);
    __hip_bfloat16* accb = qpb;
    __hip_bfloat16* xb   = vbuf;
    char* wsw = ws + HBUF_B + HALF_B;
    __hip_bfloat16* vWt   = (__hip_bfloat16*)(wsw);
    __hip_bfloat16* catWt = (__hip_bfloat16*)(wsw + 131072);
    __hip_bfloat16* outWt = (__hip_bfloat16*)(wsw + 327680);
    __hip_bfloat16* w1t   = (__hip_bfloat16*)(wsw + 458752);
    __hip_bfloat16* w2t   = (__hip_bfloat16*)(wsw + 983040);

    dim3 blk(256);

    // weights + activations prep, one launch (2944 + MP/8 = 9600 blocks)
    prep_all<<<2944 + MP / 8, blk, 0, stream>>>(
        v_W, off_W, aw_W, out_W, w1, w2, vWt, catWt, outWt, w1t, w2t,
        query, qpos, qb, qpb);

    // v-gemm + cat-gemm fused into one dispatch (2080 blocks)
    gemm_proj_pair<<<2080, blk, 0, stream>>>(
        qb, qpb, vWt, catWt, v_b, off_b, aw_b, vbuf, catb);

    // deformable sampling
    msda_sample5<<<NROW / 8, blk, 0, stream>>>(vbuf, catb, refp, accb);

    // x = LN1(qb + acc @ out_W + out_b) -> xb (bf16; bf16 residual)
    gemm_ln<true, true><<<MP / 64, blk, 0, stream>>>(
        accb, outWt, out_b, nullptr, qb, MP, ln1g, ln1b,
        nullptr, 0, xb, 256);

    // h = relu(x @ w1 + b1) -> hbuf  (wide 128x256 tile, 4x416 grid)
    gemm_wide<<<dim3(4, MP / 128), blk, 0, stream>>>(xb, w1t, b1, hbuf);

    // out = LN2(x + h @ w2 + b2)  (single launch)
    gemm_ln<false, true><<<MP / 64, blk, 0, stream>>>(
        hbuf, w2t, b2, nullptr, xb, MP, ln2g, ln2b,
        out, NROW, nullptr, 1024);
}

// Round 17
// 330.455 us; speedup vs baseline: 1.0942x; 1.0942x over previous
//
#include <hip/hip_runtime.h>
#include <hip/hip_bf16.h>
#include <cstddef>

// ---------------- problem constants ----------------
constexpr int Ll   = 13294;
constexpr int NROW = 4 * Ll;     // 53176
constexpr int MP   = 53248;      // rows padded to multiple of 128

typedef __bf16       bf8v __attribute__((ext_vector_type(8)));
typedef __bf16       bf2v __attribute__((ext_vector_type(2)));
typedef float        f4v  __attribute__((ext_vector_type(4)));
typedef unsigned int u4v  __attribute__((ext_vector_type(4)));

#if defined(__has_builtin)
#  if __has_builtin(__builtin_amdgcn_fdot2_f32_bf16)
#    define HAVE_DOT2_BF16 1
#  endif
#endif
#ifndef HAVE_DOT2_BF16
#  define HAVE_DOT2_BF16 0
#endif

// drain own loads (vm + lds) then raw barrier  [T3/T4 minimum-2-phase recipe]
#define WAIT_BARRIER() do { \
    asm volatile("s_waitcnt vmcnt(0) lgkmcnt(0)" ::: "memory"); \
    __builtin_amdgcn_s_barrier(); } while (0)

// XCD-aware chunked remap (requires nwg % 8 == 0)  [T1, m157/m192]
__device__ __forceinline__ void xcd_remap(int& m0, int& n0)
{
    const int nwg  = gridDim.x * gridDim.y;
    const int flat = blockIdx.y * gridDim.x + blockIdx.x;
    const int w    = (flat & 7) * (nwg >> 3) + (flat >> 3);
    n0 = (w % gridDim.x) * 128;
    m0 = (w / gridDim.x) * 128;
}

__device__ __forceinline__ void gload16(const __hip_bfloat16* src, __hip_bfloat16* dst)
{
    __builtin_amdgcn_global_load_lds(
        (const __attribute__((address_space(1))) void*)src,
        (__attribute__((address_space(3))) void*)dst, 16, 0, 0);
}

// =====================================================================
// shared GEMM body: 128x128 tile, BK=32 double-buffered, prefetch-before-
// compute (T3 minimum-2-phase), 4 waves 2x2, global_load_lds 16B.
// Swapped-operand MFMA: thread owns 4 consecutive output cols:
// row = m0+wm*64+mr*16+fr, col = n0+wn*64+nr*16+fq*4+j.
// A: [M][K] bf16 row-major. Bt: [N][K] bf16 (W^T). bias2: cols >= 256.
// =====================================================================
template<bool RELU, bool OUTF, bool OUTB>
__device__ __forceinline__
void gemm_body(const __hip_bfloat16* __restrict__ A, const __hip_bfloat16* __restrict__ Bt,
               const float* __restrict__ bias, const float* __restrict__ bias2,
               float* __restrict__ Cf, __hip_bfloat16* __restrict__ Cb,
               int N, int K, int m0, int n0,
               __hip_bfloat16 (*As)[128 * 32], __hip_bfloat16 (*Bs)[128 * 32])
{
    const int tid  = threadIdx.x;
    const int wid  = tid >> 6;
    const int lane = tid & 63;
    const int wm = wid >> 1, wn = wid & 1;
    const int fr = lane & 15, fq = lane >> 4;
    const int sr = lane >> 2;
    const int sc = (lane & 3) * 8;

    f4v acc[4][4] = {};   // [nr][mr]

    auto stage = [&](int buf, int kk) {
        #pragma unroll
        for (int i = 0; i < 2; ++i) {
            const int s = wid * 2 + i;
            gload16(A  + (size_t)(m0 + s * 16 + sr) * K + kk + sc, &As[buf][s * 512]);
            gload16(Bt + (size_t)(n0 + s * 16 + sr) * K + kk + sc, &Bs[buf][s * 512]);
        }
    };
    auto compute = [&](int buf) {
        bf8v a[4], b[4];
        #pragma unroll
        for (int r = 0; r < 4; ++r) {
            a[r] = __builtin_bit_cast(bf8v, *(const u4v*)&As[buf][(wm * 64 + r * 16 + fr) * 32 + fq * 8]);
            b[r] = __builtin_bit_cast(bf8v, *(const u4v*)&Bs[buf][(wn * 64 + r * 16 + fr) * 32 + fq * 8]);
        }
        __builtin_amdgcn_s_setprio(1);
        #pragma unroll
        for (int nr = 0; nr < 4; ++nr)
            #pragma unroll
            for (int mr = 0; mr < 4; ++mr)
                acc[nr][mr] = __builtin_amdgcn_mfma_f32_16x16x32_bf16(b[nr], a[mr], acc[nr][mr], 0, 0, 0);
        __builtin_amdgcn_s_setprio(0);
    };

    // prologue
    stage(0, 0);
    WAIT_BARRIER();
    for (int k0 = 0; k0 < K; k0 += 64) {
        stage(1, k0 + 32);       // issue next half's loads
        compute(0);              // compute current (loads drain under MFMA)
        WAIT_BARRIER();
        if (k0 + 64 < K) stage(0, k0 + 64);
        compute(1);
        WAIT_BARRIER();
    }

    #pragma unroll
    for (int nr = 0; nr < 4; ++nr) {
        const int colbase = n0 + wn * 64 + nr * 16 + fq * 4;
        const float* bp = (bias2 != nullptr && colbase >= 256) ? (bias2 - 256) : bias;
        const float4 b4 = *(const float4*)&bp[colbase];
        #pragma unroll
        for (int mr = 0; mr < 4; ++mr) {
            const int row = m0 + wm * 64 + mr * 16 + fr;
            f4v v = acc[nr][mr];
            v[0] += b4.x; v[1] += b4.y; v[2] += b4.z; v[3] += b4.w;
            if (RELU) {
                v[0] = fmaxf(v[0], 0.f); v[1] = fmaxf(v[1], 0.f);
                v[2] = fmaxf(v[2], 0.f); v[3] = fmaxf(v[3], 0.f);
            }
            if (OUTF)
                *(float4*)&Cf[(size_t)row * N + colbase] = make_float4(v[0], v[1], v[2], v[3]);
            if (OUTB) {
                union { ushort4 u; __hip_bfloat16 h[4]; } pk;
                pk.h[0] = __float2bfloat16(v[0]); pk.h[1] = __float2bfloat16(v[1]);
                pk.h[2] = __float2bfloat16(v[2]); pk.h[3] = __float2bfloat16(v[3]);
                *(ushort4*)&Cb[(size_t)row * N + colbase] = pk.u;
            }
        }
    }
}

// ---- standalone GEMM kernel (used for ffn1) ----
template<bool RELU, bool OUTF, bool OUTB>
__global__ __launch_bounds__(256)
void gemm_mfma(const __hip_bfloat16* __restrict__ A, const __hip_bfloat16* __restrict__ Bt,
               const float* __restrict__ bias, const float* __restrict__ bias2,
               float* __restrict__ Cf, __hip_bfloat16* __restrict__ Cb,
               int M, int N, int K)
{
    __shared__ __hip_bfloat16 As[2][128 * 32];
    __shared__ __hip_bfloat16 Bs[2][128 * 32];
    int m0, n0;
    xcd_remap(m0, n0);
    gemm_body<RELU, OUTF, OUTB>(A, Bt, bias, bias2, Cf, Cb, N, K, m0, n0, As, Bs);
}

// ---- fused v-gemm + cat-gemm: one dispatch, 2080 blocks ----
__global__ __launch_bounds__(256)
void gemm_proj_pair(const __hip_bfloat16* __restrict__ qb, const __hip_bfloat16* __restrict__ qpb,
                    const __hip_bfloat16* __restrict__ vWt, const __hip_bfloat16* __restrict__ catWt,
                    const float* __restrict__ v_b, const float* __restrict__ off_b,
                    const float* __restrict__ aw_b,
                    __hip_bfloat16* __restrict__ vbuf, __hip_bfloat16* __restrict__ catb)
{
    __shared__ __hip_bfloat16 As[2][128 * 32];
    __shared__ __hip_bfloat16 Bs[2][128 * 32];
    const int nwg  = 2080;                         // 5 * 416, %8 == 0
    const int flat = blockIdx.x;
    const int w    = (flat & 7) * (nwg >> 3) + (flat >> 3);
    const int n    = w % 5, m = w / 5;
    if (n < 2)
        gemm_body<false, false, true>(qb, vWt, v_b, nullptr,
                                      nullptr, vbuf, 256, 256, m * 128, n * 128, As, Bs);
    else
        gemm_body<false, false, true>(qpb, catWt, off_b, aw_b,
                                      nullptr, catb, 384, 256, m * 128, (n - 2) * 128, As, Bs);
}

// =====================================================================
// bf16 MFMA GEMM (64x256 tile, N fixed 256, BK=32 double-buffered,
// prefetch-before-compute) + residual + LayerNorm epilogue.
// 4 waves 2x2, wave = 32 rows x 128 cols.
// =====================================================================
template<bool STOREB, bool RESB>
__global__ __launch_bounds__(256)
void gemm_ln(const __hip_bfloat16* __restrict__ A, const __hip_bfloat16* __restrict__ Bt,
             const float* __restrict__ bias,
             const float* __restrict__ resF, const __hip_bfloat16* __restrict__ resB,
             int Mres,
             const float* __restrict__ g, const float* __restrict__ be,
             float* __restrict__ outF, int MstoreF,
             __hip_bfloat16* __restrict__ outB,
             int K)
{
    __shared__ __hip_bfloat16 As[2][64 * 32];
    __shared__ __hip_bfloat16 Bs[2][256 * 32];
    __shared__ float red[2][64][2];
    const int tid  = threadIdx.x;
    const int wid  = tid >> 6;
    const int lane = tid & 63;
    const int m0 = blockIdx.x * 64;
    const int wm = wid >> 1, wn = wid & 1;     // wave: 32 rows x 128 cols
    const int fr = lane & 15, fq = lane >> 4;
    const int sr = lane >> 2;
    const int sc = (lane & 3) * 8;

    f4v acc[8][2] = {};   // [nr][mr]

    auto stage = [&](int buf, int kk) {
        gload16(A + (size_t)(m0 + wid * 16 + sr) * K + kk + sc, &As[buf][wid * 512]);
        #pragma unroll
        for (int i = 0; i < 4; ++i) {
            const int s = wid * 4 + i;
            gload16(Bt + (size_t)(s * 16 + sr) * K + kk + sc, &Bs[buf][s * 512]);
        }
    };
    auto compute = [&](int buf) {
        bf8v a[2], b[8];
        #pragma unroll
        for (int r = 0; r < 2; ++r)
            a[r] = __builtin_bit_cast(bf8v, *(const u4v*)&As[buf][(wm * 32 + r * 16 + fr) * 32 + fq * 8]);
        #pragma unroll
        for (int r = 0; r < 8; ++r)
            b[r] = __builtin_bit_cast(bf8v, *(const u4v*)&Bs[buf][(wn * 128 + r * 16 + fr) * 32 + fq * 8]);
        __builtin_amdgcn_s_setprio(1);
        #pragma unroll
        for (int nr = 0; nr < 8; ++nr)
            #pragma unroll
            for (int mr = 0; mr < 2; ++mr)
                acc[nr][mr] = __builtin_amdgcn_mfma_f32_16x16x32_bf16(b[nr], a[mr], acc[nr][mr], 0, 0, 0);
        __builtin_amdgcn_s_setprio(0);
    };

    stage(0, 0);
    WAIT_BARRIER();
    for (int k0 = 0; k0 < K; k0 += 64) {
        stage(1, k0 + 32);
        compute(0);
        WAIT_BARRIER();
        if (k0 + 64 < K) stage(0, k0 + 64);
        compute(1);
        WAIT_BARRIER();
    }

    float s2[2] = {}, q2[2] = {};
    #pragma unroll
    for (int nr = 0; nr < 8; ++nr) {
        const int colbase = wn * 128 + nr * 16 + fq * 4;
        const float4 b4 = *(const float4*)&bias[colbase];
        #pragma unroll
        for (int mr = 0; mr < 2; ++mr) {
            const int row = m0 + wm * 32 + mr * 16 + fr;
            f4v x = acc[nr][mr];
            x[0] += b4.x; x[1] += b4.y; x[2] += b4.z; x[3] += b4.w;
            if (RESB) {
                const ushort4 r4 = *(const ushort4*)&resB[(size_t)row * 256 + colbase];
                x[0] += __builtin_bit_cast(float, (unsigned)r4.x << 16);
                x[1] += __builtin_bit_cast(float, (unsigned)r4.y << 16);
                x[2] += __builtin_bit_cast(float, (unsigned)r4.z << 16);
                x[3] += __builtin_bit_cast(float, (unsigned)r4.w << 16);
            } else if (row < Mres) {
                const float4 r4 = *(const float4*)&resF[(size_t)row * 256 + colbase];
                x[0] += r4.x; x[1] += r4.y; x[2] += r4.z; x[3] += r4.w;
            }
            acc[nr][mr] = x;
            s2[mr] += x[0] + x[1] + x[2] + x[3];
            q2[mr] += x[0]*x[0] + x[1]*x[1] + x[2]*x[2] + x[3]*x[3];
        }
    }
    #pragma unroll
    for (int mr = 0; mr < 2; ++mr) {
        s2[mr] += __shfl_xor(s2[mr], 16, 64);
        q2[mr] += __shfl_xor(q2[mr], 16, 64);
        s2[mr] += __shfl_xor(s2[mr], 32, 64);
        q2[mr] += __shfl_xor(q2[mr], 32, 64);
    }
    if (fq == 0) {
        #pragma unroll
        for (int mr = 0; mr < 2; ++mr) {
            red[wn][wm * 32 + mr * 16 + fr][0] = s2[mr];
            red[wn][wm * 32 + mr * 16 + fr][1] = q2[mr];
        }
    }
    __syncthreads();
    float mean[2], rinv[2];
    #pragma unroll
    for (int mr = 0; mr < 2; ++mr) {
        const int r = wm * 32 + mr * 16 + fr;
        const float ss = red[0][r][0] + red[1][r][0];
        const float qq = red[0][r][1] + red[1][r][1];
        mean[mr] = ss * (1.f / 256.f);
        const float var = qq * (1.f / 256.f) - mean[mr] * mean[mr];
        rinv[mr] = rsqrtf(var + 1e-5f);
    }
    #pragma unroll
    for (int nr = 0; nr < 8; ++nr) {
        const int colbase = wn * 128 + nr * 16 + fq * 4;
        const float4 g4 = *(const float4*)&g[colbase];
        const float4 e4 = *(const float4*)&be[colbase];
        #pragma unroll
        for (int mr = 0; mr < 2; ++mr) {
            const int row = m0 + wm * 32 + mr * 16 + fr;
            const f4v x = acc[nr][mr];
            float y0 = (x[0] - mean[mr]) * rinv[mr] * g4.x + e4.x;
            float y1 = (x[1] - mean[mr]) * rinv[mr] * g4.y + e4.y;
            float y2 = (x[2] - mean[mr]) * rinv[mr] * g4.z + e4.z;
            float y3 = (x[3] - mean[mr]) * rinv[mr] * g4.w + e4.w;
            if (row < MstoreF)
                *(float4*)&outF[(size_t)row * 256 + colbase] = make_float4(y0, y1, y2, y3);
            if (STOREB) {
                union { ushort4 u; __hip_bfloat16 h[4]; } pk;
                pk.h[0] = __float2bfloat16(y0); pk.h[1] = __float2bfloat16(y1);
                pk.h[2] = __float2bfloat16(y2); pk.h[3] = __float2bfloat16(y3);
                *(ushort4*)&outB[(size_t)row * 256 + colbase] = pk.u;
            }
        }
    }
}

// =====================================================================
// prep_all: weight transpose+cvt (blocks 0..2943) and query/query+pos
// bf16 conversion (blocks 2944..9599) in ONE launch.
// =====================================================================
__global__ __launch_bounds__(256)
void prep_all(const float* __restrict__ vW, const float* __restrict__ offW,
              const float* __restrict__ awW, const float* __restrict__ outW,
              const float* __restrict__ w1, const float* __restrict__ w2,
              __hip_bfloat16* __restrict__ vWt, __hip_bfloat16* __restrict__ catWt,
              __hip_bfloat16* __restrict__ outWt, __hip_bfloat16* __restrict__ w1t,
              __hip_bfloat16* __restrict__ w2t,
              const float* __restrict__ q, const float* __restrict__ qp,
              __hip_bfloat16* __restrict__ qb, __hip_bfloat16* __restrict__ qpb)
{
    if (blockIdx.x < 2944) {
        int i = blockIdx.x * 256 + threadIdx.x;   // 753664 total
        if (i < 65536) { const int n = i >> 8, k = i & 255;
            vWt[i] = __float2bfloat16(vW[(size_t)k * 256 + n]); return; }
        i -= 65536;
        if (i < 98304) { const int n = i >> 8, k = i & 255;
            catWt[i] = __float2bfloat16(n < 256 ? offW[(size_t)k * 256 + n]
                                                : awW[(size_t)k * 128 + n - 256]); return; }
        i -= 98304;
        if (i < 65536) { const int n = i >> 8, k = i & 255;
            outWt[i] = __float2bfloat16(outW[(size_t)k * 256 + n]); return; }
        i -= 65536;
        if (i < 262144) { const int n = i >> 8, k = i & 255;
            w1t[i] = __float2bfloat16(w1[(size_t)k * 1024 + n]); return; }
        i -= 262144;
        { const int n = i >> 10, k = i & 1023;
            w2t[i] = __float2bfloat16(w2[(size_t)k * 256 + n]); }
        return;
    }
    const int i   = (blockIdx.x - 2944) * 256 + threadIdx.x;  // 8-elem chunk id
    const int row = i >> 5;
    union { u4v u; __hip_bfloat16 h[8]; } p1, p2;
    if (row >= NROW) {
        u4v z = {0u, 0u, 0u, 0u};
        p1.u = z; p2.u = z;
    } else {
        const size_t e = (size_t)i * 8;
        float4 x0 = *(const float4*)&q[e];
        float4 x1 = *(const float4*)&q[e + 4];
        float4 y0 = *(const float4*)&qp[e];
        float4 y1 = *(const float4*)&qp[e + 4];
        p1.h[0] = __float2bfloat16(x0.x); p1.h[1] = __float2bfloat16(x0.y);
        p1.h[2] = __float2bfloat16(x0.z); p1.h[3] = __float2bfloat16(x0.w);
        p1.h[4] = __float2bfloat16(x1.x); p1.h[5] = __float2bfloat16(x1.y);
        p1.h[6] = __float2bfloat16(x1.z); p1.h[7] = __float2bfloat16(x1.w);
        p2.h[0] = __float2bfloat16(x0.x + y0.x); p2.h[1] = __float2bfloat16(x0.y + y0.y);
        p2.h[2] = __float2bfloat16(x0.z + y0.z); p2.h[3] = __float2bfloat16(x0.w + y0.w);
        p2.h[4] = __float2bfloat16(x1.x + y1.x); p2.h[5] = __float2bfloat16(x1.y + y1.y);
        p2.h[6] = __float2bfloat16(x1.z + y1.z); p2.h[7] = __float2bfloat16(x1.w + y1.w);
    }
    *(u4v*)&qb[(size_t)i * 8]  = p1.u;
    *(u4v*)&qpb[(size_t)i * 8] = p2.u;
}

// =====================================================================
// MSDA sampling v5: bf16 cat input, packed weights, dot2 path,
// bijective XCD-chunked block remap. 40 VGPR / ~60% occupancy.
// At the L2-line-bandwidth roofline (~33 TB/s) — closed.
// =====================================================================
__device__ __forceinline__ float blo(unsigned u) { return __builtin_bit_cast(float, u << 16); }
__device__ __forceinline__ float bhi(unsigned u) { return __builtin_bit_cast(float, u & 0xffff0000u); }

__global__ __launch_bounds__(256)
void msda_sample5(const __hip_bfloat16* __restrict__ v, const __hip_bfloat16* __restrict__ cat,
                  const float* __restrict__ refp, __hip_bfloat16* __restrict__ accO)
{
    __shared__ int      sIdx[1024][4];
    __shared__ unsigned sWpk[1024][2];   // (w0,w1),(w2,w3) packed bf16
    // bijective XCD chunked remap (nwg = 6647 = 8*830+7 -> r=7, q=830) [m204]
    int blk;
    {
        const int nwg  = gridDim.x;
        const int q    = nwg >> 3;            // 830
        const int r    = nwg & 7;             // 7
        const int xcd  = blockIdx.x & 7;
        const int off  = blockIdx.x >> 3;
        blk = (xcd < r ? xcd * (q + 1) : r * (q + 1) + (xcd - r) * q) + off;
    }
    const int row0 = blk * 8;
    const int tid  = threadIdx.x;

    #pragma unroll
    for (int it = 0; it < 4; ++it) {
        const int item = it * 256 + tid;          // (r<<7)|(h<<4)|p
        const int p = item & 15, h = (item >> 4) & 7, r = item >> 7;
        const int row = row0 + r;
        const int lvl = p >> 2;
        const float logit = __bfloat162float(cat[(size_t)row * 384 + 256 + h * 16 + p]);
        float mx = logit;
        #pragma unroll
        for (int o = 1; o < 16; o <<= 1) mx = fmaxf(mx, __shfl_xor(mx, o, 64));
        const float e = __expf(logit - mx);
        float s = e;
        #pragma unroll
        for (int o = 1; o < 16; o <<= 1) s += __shfl_xor(s, o, 64);
        const float aw = e / s;

        const int Hs_[4] = {100, 50, 25, 13};
        const int Ss[4]  = {0, 10000, 12500, 13125};
        const int   Wl = Hs_[lvl];
        const float Wf = (float)Wl;
        const float ox = __bfloat162float(cat[(size_t)row * 384 + h * 32 + p * 2 + 0]);
        const float oy = __bfloat162float(cat[(size_t)row * 384 + h * 32 + p * 2 + 1]);
        const float rx = refp[(size_t)row * 8 + lvl * 2 + 0];
        const float ry = refp[(size_t)row * 8 + lvl * 2 + 1];
        const float x = (rx + ox / Wf) * Wf - 0.5f;
        const float y = (ry + oy / Wf) * Wf - 0.5f;
        const float x0f = floorf(x), y0f = floorf(y);
        const float lx = x - x0f, ly = y - y0f;
        const int x0 = (int)x0f, y0 = (int)y0f;
        const int b = row / Ll;
        const int vbase = b * Ll + Ss[lvl];
        int ixr[4]; unsigned short wb[4];
        #pragma unroll
        for (int c = 0; c < 4; ++c) {
            const int cy = c >> 1, cx = c & 1;
            const int yi = y0 + cy, xi = x0 + cx;
            const bool ok = (yi >= 0) & (yi < Wl) & (xi >= 0) & (xi < Wl);
            const int yc = min(max(yi, 0), Wl - 1);
            const int xc = min(max(xi, 0), Wl - 1);
            const float wt = (cy ? ly : 1.f - ly) * (cx ? lx : 1.f - lx);
            ixr[c] = (vbase + yc * Wl + xc) * 512;
            const __hip_bfloat16 hw = __float2bfloat16(ok ? aw * wt : 0.f);
            wb[c] = __builtin_bit_cast(unsigned short, hw);
        }
        const int item2 = (item & ~15) | ((item & 15) ^ h);  // bank swizzle
        *(int4*)&sIdx[item2][0] = make_int4(ixr[0], ixr[1], ixr[2], ixr[3]);
        sWpk[item2][0] = (unsigned)wb[0] | ((unsigned)wb[1] << 16);
        sWpk[item2][1] = (unsigned)wb[2] | ((unsigned)wb[3] << 16);
    }
    __syncthreads();

    const int r   = tid >> 5;
    const int h   = (tid >> 2) & 7;
    const int oct = tid & 3;
    const int row = row0 + r;
    const char* vB = (const char*)v + (h * 32 + oct * 8) * 2;
    const int ibase = r * 128 + h * 16;
    float acc[8] = {};
    #pragma unroll
    for (int i = 0; i < 16; ++i) {
        const int idx = ibase + (i ^ h);
        const int4  ix = *(const int4*)&sIdx[idx][0];
        const uint2 wp = *(const uint2*)&sWpk[idx][0];
        u4v u0 = *(const u4v*)(vB + (unsigned)ix.x);
        u4v u1 = *(const u4v*)(vB + (unsigned)ix.y);
        u4v u2 = *(const u4v*)(vB + (unsigned)ix.z);
        u4v u3 = *(const u4v*)(vB + (unsigned)ix.w);
#if HAVE_DOT2_BF16
        const bf2v w01 = __builtin_bit_cast(bf2v, wp.x);
        const bf2v w23 = __builtin_bit_cast(bf2v, wp.y);
        #pragma unroll
        for (int q = 0; q < 4; ++q) {
            const unsigned lo01 = __builtin_amdgcn_perm(u1[q], u0[q], 0x05040100u);
            const unsigned hi01 = __builtin_amdgcn_perm(u1[q], u0[q], 0x07060302u);
            const unsigned lo23 = __builtin_amdgcn_perm(u3[q], u2[q], 0x05040100u);
            const unsigned hi23 = __builtin_amdgcn_perm(u3[q], u2[q], 0x07060302u);
            acc[2*q]   = __builtin_amdgcn_fdot2_f32_bf16(__builtin_bit_cast(bf2v, lo01), w01, acc[2*q],   false);
            acc[2*q]   = __builtin_amdgcn_fdot2_f32_bf16(__builtin_bit_cast(bf2v, lo23), w23, acc[2*q],   false);
            acc[2*q+1] = __builtin_amdgcn_fdot2_f32_bf16(__builtin_bit_cast(bf2v, hi01), w01, acc[2*q+1], false);
            acc[2*q+1] = __builtin_amdgcn_fdot2_f32_bf16(__builtin_bit_cast(bf2v, hi23), w23, acc[2*q+1], false);
        }
#else
        const float w0 = blo(wp.x), w1 = bhi(wp.x);
        const float w2 = blo(wp.y), w3 = bhi(wp.y);
        #pragma unroll
        for (int q = 0; q < 4; ++q) {
            acc[2*q]   = fmaf(w0, blo(u0[q]), acc[2*q]);
            acc[2*q+1] = fmaf(w0, bhi(u0[q]), acc[2*q+1]);
            acc[2*q]   = fmaf(w1, blo(u1[q]), acc[2*q]);
            acc[2*q+1] = fmaf(w1, bhi(u1[q]), acc[2*q+1]);
            acc[2*q]   = fmaf(w2, blo(u2[q]), acc[2*q]);
            acc[2*q+1] = fmaf(w2, bhi(u2[q]), acc[2*q+1]);
            acc[2*q]   = fmaf(w3, blo(u3[q]), acc[2*q]);
            acc[2*q+1] = fmaf(w3, bhi(u3[q]), acc[2*q+1]);
        }
#endif
    }
    union { u4v u; __hip_bfloat16 hh[8]; } pk;
    #pragma unroll
    for (int q = 0; q < 8; ++q) pk.hh[q] = __float2bfloat16(acc[q]);
    *(u4v*)&accO[(size_t)row * 256 + h * 32 + oct * 8] = pk.u;
}

// =====================================================================
// launcher
// =====================================================================
extern "C" void kernel_launch(void* const* d_in, const int* in_sizes, int n_in,
                              void* d_out, int out_size, void* d_ws, size_t ws_size,
                              hipStream_t stream)
{
    (void)in_sizes; (void)n_in; (void)out_size; (void)ws_size;
    const float* query = (const float*)d_in[0];
    const float* qpos  = (const float*)d_in[1];
    const float* refp  = (const float*)d_in[2];
    const float* v_W   = (const float*)d_in[5];
    const float* v_b   = (const float*)d_in[6];
    const float* off_W = (const float*)d_in[7];
    const float* off_b = (const float*)d_in[8];
    const float* aw_W  = (const float*)d_in[9];
    const float* aw_b  = (const float*)d_in[10];
    const float* out_W = (const float*)d_in[11];
    const float* out_b = (const float*)d_in[12];
    const float* ln1g  = (const float*)d_in[13];
    const float* ln1b  = (const float*)d_in[14];
    const float* w1    = (const float*)d_in[15];
    const float* b1    = (const float*)d_in[16];
    const float* w2    = (const float*)d_in[17];
    const float* b2    = (const float*)d_in[18];
    const float* ln2g  = (const float*)d_in[19];
    const float* ln2b  = (const float*)d_in[20];
    float* out = (float*)d_out;

    char* ws = (char*)d_ws;
    // arena (peak ~137.9 MB) — live-range audited (round-11 layout):
    //   hbuf bf16 [MP][1024] : [0, 109.1M)            (written ffn1, read ffn2)
    //     inside hbuf's span, dead before ffn1:
    //     qb   bf16 [0, 27.3M)        (prep -> v-gemm A, LN1 residual; dead after LN1)
    //     qpb  bf16 [27.3M, 54.6M)    (prep -> cat-gemm A; reused as accb after)
    //     catb bf16 [54.6M, 95.5M)    (cat-gemm out -> msda; dead after msda)
    //   vbuf/xb bf16 [109.1M, 136.4M)  (v-gemm out -> msda; xb = LN1 out, live thru ffn2)
    //   weights [136.4M, 137.9M)
    constexpr size_t HALF_B = (size_t)MP * 256 * 2;     //  27,262,976
    constexpr size_t HBUF_B = (size_t)MP * 1024 * 2;    // 109,051,904
    __hip_bfloat16* hbuf = (__hip_bfloat16*)ws;
    __hip_bfloat16* qb   = (__hip_bfloat16*)ws;
    __hip_bfloat16* qpb  = (__hip_bfloat16*)(ws + HALF_B);
    __hip_bfloat16* catb = (__hip_bfloat16*)(ws + 2 * HALF_B);
    __hip_bfloat16* vbuf = (__hip_bfloat16*)(ws + HBUF_B);
    __hip_bfloat16* accb = qpb;
    __hip_bfloat16* xb   = vbuf;
    char* wsw = ws + HBUF_B + HALF_B;
    __hip_bfloat16* vWt   = (__hip_bfloat16*)(wsw);
    __hip_bfloat16* catWt = (__hip_bfloat16*)(wsw + 131072);
    __hip_bfloat16* outWt = (__hip_bfloat16*)(wsw + 327680);
    __hip_bfloat16* w1t   = (__hip_bfloat16*)(wsw + 458752);
    __hip_bfloat16* w2t   = (__hip_bfloat16*)(wsw + 983040);

    dim3 blk(256);

    // weights + activations prep, one launch (2944 + MP/8 = 9600 blocks)
    prep_all<<<2944 + MP / 8, blk, 0, stream>>>(
        v_W, off_W, aw_W, out_W, w1, w2, vWt, catWt, outWt, w1t, w2t,
        query, qpos, qb, qpb);

    // v-gemm + cat-gemm fused into one dispatch (2080 blocks)
    gemm_proj_pair<<<2080, blk, 0, stream>>>(
        qb, qpb, vWt, catWt, v_b, off_b, aw_b, vbuf, catb);

    // deformable sampling
    msda_sample5<<<NROW / 8, blk, 0, stream>>>(vbuf, catb, refp, accb);

    // x = LN1(qb + acc @ out_W + out_b) -> xb (bf16; bf16 residual)
    gemm_ln<true, true><<<MP / 64, blk, 0, stream>>>(
        accb, outWt, out_b, nullptr, qb, MP, ln1g, ln1b,
        nullptr, 0, xb, 256);

    // h = relu(x @ w1 + b1) -> hbuf  (single launch, 128x128 tiles)
    gemm_mfma<true, false, true><<<dim3(8, MP / 128), blk, 0, stream>>>(
        xb, w1t, b1, nullptr, nullptr, hbuf, MP, 1024, 256);

    // out = LN2(x + h @ w2 + b2)  (single launch)
    gemm_ln<false, true><<<MP / 64, blk, 0, stream>>>(
        hbuf, w2t, b2, nullptr, xb, MP, ln2g, ln2b,
        out, NROW, nullptr, 1024);
}